// Round 14
// baseline (917.074 us; speedup 1.0000x reference)
//
#include <hip/hip_runtime.h>
#include <hip/hip_bf16.h>

// Problem constants
#define TT 512
#define BB 256
#define II 120
#define HH 128
#define GG 512   // 4*H
#define D1 512
#define NOUT 7
#define TB (TT*BB)  // 131072

typedef _Float16 f16x2 __attribute__((ext_vector_type(2)));
typedef _Float16 f16x4 __attribute__((ext_vector_type(4)));
typedef _Float16 f16x8 __attribute__((ext_vector_type(8)));
typedef float    f32x4 __attribute__((ext_vector_type(4)));

// ---------- static device scratch ----------
__device__ unsigned short g_xg[(size_t)TB * GG];   // [T*B, 512] bf16
__device__ _Float16       g_h0[(size_t)TB * HH];   // [T*B, 128] f16
__device__ float          g_pooled[BB * HH];

// ---------- helpers ----------
__device__ inline float bf2f(unsigned short u) {
    return __uint_as_float(((unsigned)u) << 16);
}
__device__ inline unsigned short f2bf(float f) {
    unsigned u = __float_as_uint(f);
    return (unsigned short)((u + 0x7fffu + ((u >> 16) & 1u)) >> 16);
}
__device__ inline float sigm(float x) {
    return 1.0f / (1.0f + __expf(-x));
}
__device__ inline float tanh_fast(float x) {
    x = fminf(fmaxf(x, -15.f), 15.f);
    float e = __expf(2.f * x);
    return (e - 1.f) / (e + 1.f);
}

// ---------- MFMA GEMM: xg[n,g] = sum_k A[n,k]*W[g,k] + bia[g]+bib[g] ----------
// f16 MFMA 16x16x32. Block: 128(M)x128(N), 512 threads = 8 waves (2x4 of 64x32).
template <int LAYER>
__global__ __launch_bounds__(512) void gemm_mfma_kernel(
    const float* __restrict__ A0,     // [TB, II] (LAYER 0 only)
    const float* __restrict__ W,      // [512, F] f32
    const float* __restrict__ bia,
    const float* __restrict__ bib)
{
    const int F  = (LAYER == 0) ? II : HH;
    const int m0 = blockIdx.x * 128;
    const int n0 = blockIdx.y * 128;
    const int t    = threadIdx.x;
    const int lane = t & 63;
    const int wv   = t >> 6;         // 0..7
    const int wm   = wv >> 2;        // 0..1 -> rows wm*64
    const int wn   = wv & 3;         // 0..3 -> cols wn*32
    const int l15  = lane & 15;
    const int lhi  = lane >> 4;      // 0..3

    __shared__ _Float16 As[128][40];
    __shared__ _Float16 Bs[128][40];

    f32x4 acc[4][2];
#pragma unroll
    for (int mi = 0; mi < 4; ++mi)
#pragma unroll
        for (int ni = 0; ni < 2; ++ni)
            acc[mi][ni] = f32x4{0.f, 0.f, 0.f, 0.f};

    const int srow = t >> 2;   // staging row 0..127
    const int q    = t & 3;    // k-slot: covers k0+q*8 .. +7

#pragma unroll 1
    for (int kc = 0; kc < 4; ++kc) {
        const int k0 = kc * 32;
        if (LAYER == 0) {
#pragma unroll
            for (int h = 0; h < 2; ++h) {
                int k = k0 + q * 8 + h * 4;
                float4 v = make_float4(0.f, 0.f, 0.f, 0.f);
                if (k + 4 <= F) v = *(const float4*)&A0[(size_t)(m0 + srow) * II + k];
                f16x4 hv = {(_Float16)v.x, (_Float16)v.y, (_Float16)v.z, (_Float16)v.w};
                *(f16x4*)&As[srow][q * 8 + h * 4] = hv;
            }
        } else {
            int k = k0 + q * 8;   // F=128: always valid
            f16x8 v = *(const f16x8*)&g_h0[(size_t)(m0 + srow) * HH + k];
            *(f16x8*)&As[srow][q * 8] = v;
        }
#pragma unroll
        for (int h = 0; h < 2; ++h) {
            int k = k0 + q * 8 + h * 4;
            float4 v = make_float4(0.f, 0.f, 0.f, 0.f);
            if (k + 4 <= F) v = *(const float4*)&W[(size_t)(n0 + srow) * F + k];
            f16x4 hv = {(_Float16)v.x, (_Float16)v.y, (_Float16)v.z, (_Float16)v.w};
            *(f16x4*)&Bs[srow][q * 8 + h * 4] = hv;
        }
        __syncthreads();

        f16x8 af[4], bfv[2];
#pragma unroll
        for (int mi = 0; mi < 4; ++mi)
            af[mi] = *(const f16x8*)&As[wm * 64 + mi * 16 + l15][lhi * 8];
#pragma unroll
        for (int ni = 0; ni < 2; ++ni)
            bfv[ni] = *(const f16x8*)&Bs[wn * 32 + ni * 16 + l15][lhi * 8];
#pragma unroll
        for (int mi = 0; mi < 4; ++mi)
#pragma unroll
            for (int ni = 0; ni < 2; ++ni)
                acc[mi][ni] = __builtin_amdgcn_mfma_f32_16x16x32_f16(
                    af[mi], bfv[ni], acc[mi][ni], 0, 0, 0);
        __syncthreads();
    }

#pragma unroll
    for (int ni = 0; ni < 2; ++ni) {
        const int col = n0 + wn * 32 + ni * 16 + l15;
        const float bc = bia[col] + bib[col];
#pragma unroll
        for (int mi = 0; mi < 4; ++mi) {
#pragma unroll
            for (int j = 0; j < 4; ++j) {
                const int grow = m0 + wm * 64 + mi * 16 + lhi * 4 + j;
                g_xg[(size_t)grow * GG + col] = f2bf(acc[mi][ni][j] + bc);
            }
        }
    }
}

// ---------- LSTM recurrence: replicated-M MFMA, 256 blocks, 512 threads ----------
// One block per batch elem (256 CUs stay busy -> transcendental work spread).
// The recurrent matmul h(1x128) x Whh^T(128x512) runs on the MATRIX pipe:
// A-frag = h broadcast into all 16 M-rows (one ds_read_b128 broadcast per
// 32-K chunk; all D rows become identical -> use reg 0 of each f32x4).
// Wave w owns gate col-tiles {w, w+8, w+16, w+24} = i,f,g,o of unit
// U = w*16 + (lane&15): cell update is fully LANE-LOCAL (no exchange at all).
// x folds into the MFMA C operand. B-frags (Whh) = 64 VGPR, asm-pinned.
// Per step/wave: 4 ds_read_b128 + 16 MFMA + 5 transcendentals + ~30 VALU.
template <int LAYER>
__global__ __launch_bounds__(512) void lstm_mfma_kernel(
    const float* __restrict__ Whh,   // [512,128]
    const int* __restrict__ lens)
{
    const int b    = blockIdx.x;
    const int t    = threadIdx.x;
    const int w    = t >> 6;       // wave 0..7
    const int lane = t & 63;
    const int l15  = lane & 15;
    const int lhi  = lane >> 4;    // 0..3
    const int U    = w * 16 + l15; // this lane's unit

    __shared__ __align__(16) _Float16 hbuf[2][HH];

    // B-frags: bfr[kd][kp] = Whh row (kd*128 + U), k = kp*32 + lhi*8 .. +7
    uint4 bfr[4][4];
#pragma unroll
    for (int kd = 0; kd < 4; ++kd) {
        const int row = kd * 128 + U;
#pragma unroll
        for (int kp = 0; kp < 4; ++kp) {
            const float* src = &Whh[(size_t)row * HH + kp * 32 + lhi * 8];
            float4 v0 = *(const float4*)(src);
            float4 v1 = *(const float4*)(src + 4);
            f16x8 f = {(_Float16)v0.x, (_Float16)v0.y, (_Float16)v0.z, (_Float16)v0.w,
                       (_Float16)v1.x, (_Float16)v1.y, (_Float16)v1.z, (_Float16)v1.w};
            bfr[kd][kp] = __builtin_bit_cast(uint4, f);
        }
    }
    // pin component-wise: loads cannot be rematerialized into the loop
#pragma unroll
    for (int kd = 0; kd < 4; ++kd)
#pragma unroll
        for (int kp = 0; kp < 4; ++kp)
            asm volatile("" : "+v"(bfr[kd][kp].x), "+v"(bfr[kd][kp].y),
                              "+v"(bfr[kd][kp].z), "+v"(bfr[kd][kp].w));

    if (t < HH) {
        hbuf[0][t] = (_Float16)0.f;
        hbuf[1][t] = (_Float16)0.f;
    }
    float c = 0.f, pool = 0.f;
    const int len = lens[b];

    const unsigned short* xb = g_xg + (size_t)b * GG + U;  // + kd*128 per gate
    const size_t xstride = (size_t)BB * GG;

    unsigned short xc[4];
#pragma unroll
    for (int kd = 0; kd < 4; ++kd) xc[kd] = xb[kd * 128];
    __syncthreads();

    for (int s = 0; s < TT; ++s) {
        unsigned short xn[4] = {0, 0, 0, 0};
        if (s + 1 < TT) {
            const unsigned short* xp = xb + (size_t)(s + 1) * xstride;
#pragma unroll
            for (int kd = 0; kd < 4; ++kd) xn[kd] = xp[kd * 128];
        }
        const int rd = s & 1, wr2 = rd ^ 1;

        // C-init = x (replicated across the 4 identical D rows)
        f32x4 acc[4];
#pragma unroll
        for (int kd = 0; kd < 4; ++kd) {
            const float xv = bf2f(xc[kd]);
            acc[kd] = f32x4{xv, xv, xv, xv};
        }
        // 16 MFMA: 4 K-chunks x 4 gate kinds; A = h broadcast (lhi-only addr)
#pragma unroll
        for (int kp = 0; kp < 4; ++kp) {
            f16x8 af = *(const f16x8*)&hbuf[rd][kp * 32 + lhi * 8];
#pragma unroll
            for (int kd = 0; kd < 4; ++kd)
                acc[kd] = __builtin_amdgcn_mfma_f32_16x16x32_f16(
                    af, __builtin_bit_cast(f16x8, bfr[kd][kp]), acc[kd], 0, 0, 0);
        }

        // gates: all 4 components of each acc are identical -> use [0]
        const float i_ = sigm(acc[0][0]);
        const float f_ = sigm(acc[1][0]);
        const float g_ = tanh_fast(acc[2][0]);
        const float o_ = sigm(acc[3][0]);
        c = f_ * c + i_ * g_;
        const float hv = o_ * tanh_fast(c);

        if (LAYER == 0) {
            if (lhi == 0) g_h0[((size_t)s * BB + b) * HH + U] = (_Float16)hv;
        } else {
            if (s < len) {
                const float ah = fabsf(hv);
                pool += ah * sqrtf(ah);   // |h|^1.5
            }
        }
        if (lhi == 0) hbuf[wr2][U] = (_Float16)hv;
        __syncthreads();
#pragma unroll
        for (int kd = 0; kd < 4; ++kd) xc[kd] = xn[kd];
    }

    if (LAYER == 1 && lhi == 0) {
        g_pooled[b * HH + U] = powf(pool, 2.f / 3.f) * powf((float)len, -2.f / 3.f);
    }
}

// ---------- MLP + softmax ----------
__global__ __launch_bounds__(512) void mlp_kernel(
    const float* __restrict__ W1, const float* __restrict__ b1,
    const float* __restrict__ W2, const float* __restrict__ b2,
    float* __restrict__ out)
{
    const int b = blockIdx.x;
    const int t = threadIdx.x;
    __shared__ __align__(16) float pl[HH];
    __shared__ float x1[D1];
    __shared__ float lg[NOUT];

    if (t < HH) pl[t] = g_pooled[b * HH + t];
    __syncthreads();

    float acc = b1[t];
#pragma unroll
    for (int k4 = 0; k4 < 32; ++k4) {
        float4 wv = *(const float4*)&W1[(size_t)t * HH + k4 * 4];
        float4 pv = *(const float4*)&pl[k4 * 4];
        acc += wv.x * pv.x + wv.y * pv.y + wv.z * pv.z + wv.w * pv.w;
    }
    x1[t] = fmaxf(acc, 0.f);
    __syncthreads();

    if (t < NOUT) {
        float a = b2[t];
        for (int d = 0; d < D1; ++d) a += x1[d] * W2[(size_t)t * D1 + d];
        lg[t] = a;
    }
    __syncthreads();
    if (t < NOUT) {
        float m = lg[0];
#pragma unroll
        for (int j = 1; j < NOUT; ++j) m = fmaxf(m, lg[j]);
        float s = 0.f;
#pragma unroll
        for (int j = 0; j < NOUT; ++j) s += __expf(lg[j] - m);
        out[b * NOUT + t] = __expf(lg[t] - m) / s;
    }
}

// ---------- launch ----------
extern "C" void kernel_launch(void* const* d_in, const int* in_sizes, int n_in,
                              void* d_out, int out_size, void* d_ws, size_t ws_size,
                              hipStream_t stream)
{
    const float* x      = (const float*)d_in[0];
    const int*   lens   = (const int*)d_in[1];
    const float* W_ih0  = (const float*)d_in[2];
    const float* W_hh0  = (const float*)d_in[3];
    const float* b_ih0  = (const float*)d_in[4];
    const float* b_hh0  = (const float*)d_in[5];
    const float* W_ih1  = (const float*)d_in[6];
    const float* W_hh1  = (const float*)d_in[7];
    const float* b_ih1  = (const float*)d_in[8];
    const float* b_hh1  = (const float*)d_in[9];
    const float* W1     = (const float*)d_in[10];
    const float* b1     = (const float*)d_in[11];
    const float* W2     = (const float*)d_in[12];
    const float* b2     = (const float*)d_in[13];
    float* out = (float*)d_out;

    dim3 gg(TB / 128, GG / 128);   // (1024, 4)
    gemm_mfma_kernel<0><<<gg, 512, 0, stream>>>(x, W_ih0, b_ih0, b_hh0);
    lstm_mfma_kernel<0><<<BB, 512, 0, stream>>>(W_hh0, lens);
    gemm_mfma_kernel<1><<<gg, 512, 0, stream>>>(x, W_ih1, b_ih1, b_hh1);
    lstm_mfma_kernel<1><<<BB, 512, 0, stream>>>(W_hh1, lens);
    mlp_kernel<<<BB, 512, 0, stream>>>(W1, b1, W2, b2, out);
}

// Round 15
// 855.359 us; speedup vs baseline: 1.0722x; 1.0722x over previous
//
#include <hip/hip_runtime.h>
#include <hip/hip_bf16.h>

// Problem constants
#define TT 512
#define BB 256
#define II 120
#define HH 128
#define GG 512   // 4*H
#define D1 512
#define NOUT 7
#define TB (TT*BB)  // 131072

typedef _Float16 f16x2 __attribute__((ext_vector_type(2)));
typedef _Float16 f16x4 __attribute__((ext_vector_type(4)));
typedef _Float16 f16x8 __attribute__((ext_vector_type(8)));
typedef float    f32x4 __attribute__((ext_vector_type(4)));

// ---------- static device scratch ----------
__device__ unsigned short g_xg[(size_t)TB * GG];   // [T*B, 512] bf16
__device__ _Float16       g_h0[(size_t)TB * HH];   // [T*B, 128] f16
__device__ float          g_pooled[BB * HH];

// ---------- helpers ----------
__device__ inline float bf2f(unsigned short u) {
    return __uint_as_float(((unsigned)u) << 16);
}
__device__ inline unsigned short f2bf(float f) {
    unsigned u = __float_as_uint(f);
    return (unsigned short)((u + 0x7fffu + ((u >> 16) & 1u)) >> 16);
}
__device__ inline float fdot2(f16x2 a, f16x2 b, float c) {
#if __has_builtin(__builtin_amdgcn_fdot2)
    return __builtin_amdgcn_fdot2(a, b, c, false);
#else
    return c + (float)a[0] * (float)b[0] + (float)a[1] * (float)b[1];
#endif
}
__device__ inline f16x2 asf16x2(float f) { return __builtin_bit_cast(f16x2, f); }
// DPP pair swap within quads: [1,0,3,2] — lanes 2u <-> 2u+1
__device__ inline float dpp_xor1(float v) {
#if __has_builtin(__builtin_amdgcn_mov_dpp)
    return __int_as_float(
        __builtin_amdgcn_mov_dpp(__float_as_int(v), 0xB1, 0xf, 0xf, true));
#else
    return __shfl_xor(v, 1, 4);
#endif
}

// ---------- MFMA GEMM: xg[n,g] = sum_k A[n,k]*W[g,k] + bia[g]+bib[g] ----------
// f16 MFMA 16x16x32. Block: 128(M)x128(N), 512 threads = 8 waves (2x4 of 64x32).
template <int LAYER>
__global__ __launch_bounds__(512) void gemm_mfma_kernel(
    const float* __restrict__ A0,     // [TB, II] (LAYER 0 only)
    const float* __restrict__ W,      // [512, F] f32
    const float* __restrict__ bia,
    const float* __restrict__ bib)
{
    const int F  = (LAYER == 0) ? II : HH;
    const int m0 = blockIdx.x * 128;
    const int n0 = blockIdx.y * 128;
    const int t    = threadIdx.x;
    const int lane = t & 63;
    const int wv   = t >> 6;         // 0..7
    const int wm   = wv >> 2;        // 0..1 -> rows wm*64
    const int wn   = wv & 3;         // 0..3 -> cols wn*32
    const int l15  = lane & 15;
    const int lhi  = lane >> 4;      // 0..3

    __shared__ _Float16 As[128][40];
    __shared__ _Float16 Bs[128][40];

    f32x4 acc[4][2];
#pragma unroll
    for (int mi = 0; mi < 4; ++mi)
#pragma unroll
        for (int ni = 0; ni < 2; ++ni)
            acc[mi][ni] = f32x4{0.f, 0.f, 0.f, 0.f};

    const int srow = t >> 2;   // staging row 0..127
    const int q    = t & 3;    // k-slot: covers k0+q*8 .. +7

#pragma unroll 1
    for (int kc = 0; kc < 4; ++kc) {
        const int k0 = kc * 32;
        if (LAYER == 0) {
#pragma unroll
            for (int h = 0; h < 2; ++h) {
                int k = k0 + q * 8 + h * 4;
                float4 v = make_float4(0.f, 0.f, 0.f, 0.f);
                if (k + 4 <= F) v = *(const float4*)&A0[(size_t)(m0 + srow) * II + k];
                f16x4 hv = {(_Float16)v.x, (_Float16)v.y, (_Float16)v.z, (_Float16)v.w};
                *(f16x4*)&As[srow][q * 8 + h * 4] = hv;
            }
        } else {
            int k = k0 + q * 8;   // F=128: always valid
            f16x8 v = *(const f16x8*)&g_h0[(size_t)(m0 + srow) * HH + k];
            *(f16x8*)&As[srow][q * 8] = v;
        }
#pragma unroll
        for (int h = 0; h < 2; ++h) {
            int k = k0 + q * 8 + h * 4;
            float4 v = make_float4(0.f, 0.f, 0.f, 0.f);
            if (k + 4 <= F) v = *(const float4*)&W[(size_t)(n0 + srow) * F + k];
            f16x4 hv = {(_Float16)v.x, (_Float16)v.y, (_Float16)v.z, (_Float16)v.w};
            *(f16x4*)&Bs[srow][q * 8 + h * 4] = hv;
        }
        __syncthreads();

        f16x8 af[4], bfv[2];
#pragma unroll
        for (int mi = 0; mi < 4; ++mi)
            af[mi] = *(const f16x8*)&As[wm * 64 + mi * 16 + l15][lhi * 8];
#pragma unroll
        for (int ni = 0; ni < 2; ++ni)
            bfv[ni] = *(const f16x8*)&Bs[wn * 32 + ni * 16 + l15][lhi * 8];
#pragma unroll
        for (int mi = 0; mi < 4; ++mi)
#pragma unroll
            for (int ni = 0; ni < 2; ++ni)
                acc[mi][ni] = __builtin_amdgcn_mfma_f32_16x16x32_f16(
                    af[mi], bfv[ni], acc[mi][ni], 0, 0, 0);
        __syncthreads();
    }

#pragma unroll
    for (int ni = 0; ni < 2; ++ni) {
        const int col = n0 + wn * 32 + ni * 16 + l15;
        const float bc = bia[col] + bib[col];
#pragma unroll
        for (int mi = 0; mi < 4; ++mi) {
#pragma unroll
            for (int j = 0; j < 4; ++j) {
                const int grow = m0 + wm * 64 + mi * 16 + lhi * 4 + j;
                g_xg[(size_t)grow * GG + col] = f2bf(acc[mi][ni][j] + bc);
            }
        }
    }
}

// ---------- LSTM recurrence: 256 threads, 1 wave/SIMD, FULL K=128 ----------
// BUGFIX vs r11-r13: the dot loop ran seg<8 (K=0..63 only) — half the
// recurrent term was silently dropped (passed only because the tolerance
// absorbed it). Restored seg<16 -> full K coverage: 128 dot2/thread.
// Thread t -> (u = t>>1, q = t&1); q=0 owns rows {u(i), 128+u(f)},
// q=1 owns {256+u(g), 384+u(o)}. Weights 128 packed VGPRs, asm-pinned
// (r13: pin raised residency VGPR 72->100 at no cost). One DPP pair swap
// exchanges gates. 1 barrier/step; h double-buffered f16 in LDS.
template <int LAYER>
__global__ __launch_bounds__(256) void lstm_kernel(
    const float* __restrict__ Whh,   // [512,128]
    const int* __restrict__ lens)
{
    const int b = blockIdx.x;
    const int t = threadIdx.x;
    const int u = t >> 1;        // unit 0..127
    const int q = t & 1;         // row-pair selector
    const int r0 = q * 256 + u;  // i (q=0) or g (q=1)
    const int r1 = r0 + 128;     // f (q=0) or o (q=1)

    __shared__ __align__(16) _Float16 h_lds[2][HH];

    float w0r[64], w1r[64];      // f16x2 bit-packed in float
#pragma unroll
    for (int k4 = 0; k4 < 32; ++k4) {
        float4 v = *(const float4*)&Whh[(size_t)r0 * HH + k4 * 4];
        w0r[k4 * 2 + 0] = __builtin_bit_cast(float, f16x2{(_Float16)v.x, (_Float16)v.y});
        w0r[k4 * 2 + 1] = __builtin_bit_cast(float, f16x2{(_Float16)v.z, (_Float16)v.w});
        float4 v2 = *(const float4*)&Whh[(size_t)r1 * HH + k4 * 4];
        w1r[k4 * 2 + 0] = __builtin_bit_cast(float, f16x2{(_Float16)v2.x, (_Float16)v2.y});
        w1r[k4 * 2 + 1] = __builtin_bit_cast(float, f16x2{(_Float16)v2.z, (_Float16)v2.w});
    }
    // PIN: opaque no-op asm -> weight loads cannot be sunk into the loop.
#pragma unroll
    for (int k = 0; k < 64; ++k) {
        asm volatile("" : "+v"(w0r[k]));
        asm volatile("" : "+v"(w1r[k]));
    }

    if (t < HH) {
        h_lds[0][t] = (_Float16)0.f;
        h_lds[1][t] = (_Float16)0.f;
    }
    float c = 0.f, pool = 0.f;
    const int len = lens[b];
    __syncthreads();

    const unsigned short* xb = g_xg + (size_t)b * GG;
    const size_t xstride = (size_t)BB * GG;
    float x0 = bf2f(xb[r0]);
    float x1 = bf2f(xb[r1]);

    // act0: q=0 -> sigm(x) ; q=1 -> tanh(x) = 2*sigm(2x)-1 (branchless)
    const float am = q ? 2.f : 1.f;    // input scale
    const float as = q ? 2.f : 1.f;    // output scale
    const float ao = q ? -1.f : 0.f;   // output offset

    for (int step = 0; step < TT; ++step) {
        float nx0 = 0.f, nx1 = 0.f;
        if (step + 1 < TT) {
            const unsigned short* xn = xb + (size_t)(step + 1) * xstride;
            nx0 = bf2f(xn[r0]);
            nx1 = bf2f(xn[r1]);
        }
        const int rd = step & 1, wr = rd ^ 1;

        // two full-K dots: 16 segs x 8 k-values. 8 independent 16-deep chains.
        float a00 = 0.f, a01 = 0.f, a02 = 0.f, a03 = 0.f;
        float a10 = 0.f, a11 = 0.f, a12 = 0.f, a13 = 0.f;
#pragma unroll
        for (int seg = 0; seg < 16; ++seg) {
            f16x8 hv = *(const f16x8*)&h_lds[rd][seg * 8];   // broadcast read
            f16x2 hA = {hv[0], hv[1]}, hB = {hv[2], hv[3]};
            f16x2 hC = {hv[4], hv[5]}, hD = {hv[6], hv[7]};
            a00 = fdot2(asf16x2(w0r[seg * 4 + 0]), hA, a00);
            a01 = fdot2(asf16x2(w0r[seg * 4 + 1]), hB, a01);
            a02 = fdot2(asf16x2(w0r[seg * 4 + 2]), hC, a02);
            a03 = fdot2(asf16x2(w0r[seg * 4 + 3]), hD, a03);
            a10 = fdot2(asf16x2(w1r[seg * 4 + 0]), hA, a10);
            a11 = fdot2(asf16x2(w1r[seg * 4 + 1]), hB, a11);
            a12 = fdot2(asf16x2(w1r[seg * 4 + 2]), hC, a12);
            a13 = fdot2(asf16x2(w1r[seg * 4 + 3]), hD, a13);
        }
        const float a0 = (a00 + a01) + (a02 + a03) + x0;
        const float a1 = (a10 + a11) + (a12 + a13) + x1;

        // activations (branchless): act0 = sigm/tanh, act1 = sigm
        const float s0 = 1.f / (1.f + __expf(-(a0 * am)));
        const float act0 = s0 * as + ao;
        const float act1 = 1.f / (1.f + __expf(-a1));

        // pair exchange: (u,0) has i,f ; (u,1) has g,o
        const float p0 = dpp_xor1(act0);
        const float p1 = dpp_xor1(act1);
        const float i_ = q ? p0 : act0;
        const float f_ = q ? p1 : act1;
        const float g_ = q ? act0 : p0;
        const float o_ = q ? act1 : p1;

        c = f_ * c + i_ * g_;
        const float e2 = __expf(-2.f * c);
        const float th = 2.f / (1.f + e2) - 1.f;
        const float hv2 = o_ * th;

        if (LAYER == 0) {
            if (q) g_h0[((size_t)step * BB + b) * HH + u] = (_Float16)hv2;
        } else {
            if (step < len) {
                const float ah = fabsf(hv2);
                pool += ah * sqrtf(ah);   // |h|^1.5
            }
        }
        if (!q) h_lds[wr][u] = (_Float16)hv2;
        __syncthreads();
        x0 = nx0;
        x1 = nx1;
    }

    if (LAYER == 1 && !q) {
        const float s = powf(pool, 2.f / 3.f) * powf((float)len, -2.f / 3.f);
        g_pooled[b * HH + u] = s;
    }
}

// ---------- MLP + softmax ----------
__global__ __launch_bounds__(512) void mlp_kernel(
    const float* __restrict__ W1, const float* __restrict__ b1,
    const float* __restrict__ W2, const float* __restrict__ b2,
    float* __restrict__ out)
{
    const int b = blockIdx.x;
    const int t = threadIdx.x;
    __shared__ __align__(16) float pl[HH];
    __shared__ float x1[D1];
    __shared__ float lg[NOUT];

    if (t < HH) pl[t] = g_pooled[b * HH + t];
    __syncthreads();

    float acc = b1[t];
#pragma unroll
    for (int k4 = 0; k4 < 32; ++k4) {
        float4 wv = *(const float4*)&W1[(size_t)t * HH + k4 * 4];
        float4 pv = *(const float4*)&pl[k4 * 4];
        acc += wv.x * pv.x + wv.y * pv.y + wv.z * pv.z + wv.w * pv.w;
    }
    x1[t] = fmaxf(acc, 0.f);
    __syncthreads();

    if (t < NOUT) {
        float a = b2[t];
        for (int d = 0; d < D1; ++d) a += x1[d] * W2[(size_t)t * D1 + d];
        lg[t] = a;
    }
    __syncthreads();
    if (t < NOUT) {
        float m = lg[0];
#pragma unroll
        for (int j = 1; j < NOUT; ++j) m = fmaxf(m, lg[j]);
        float s = 0.f;
#pragma unroll
        for (int j = 0; j < NOUT; ++j) s += __expf(lg[j] - m);
        out[b * NOUT + t] = __expf(lg[t] - m) / s;
    }
}

// ---------- launch ----------
extern "C" void kernel_launch(void* const* d_in, const int* in_sizes, int n_in,
                              void* d_out, int out_size, void* d_ws, size_t ws_size,
                              hipStream_t stream)
{
    const float* x      = (const float*)d_in[0];
    const int*   lens   = (const int*)d_in[1];
    const float* W_ih0  = (const float*)d_in[2];
    const float* W_hh0  = (const float*)d_in[3];
    const float* b_ih0  = (const float*)d_in[4];
    const float* b_hh0  = (const float*)d_in[5];
    const float* W_ih1  = (const float*)d_in[6];
    const float* W_hh1  = (const float*)d_in[7];
    const float* b_ih1  = (const float*)d_in[8];
    const float* b_hh1  = (const float*)d_in[9];
    const float* W1     = (const float*)d_in[10];
    const float* b1     = (const float*)d_in[11];
    const float* W2     = (const float*)d_in[12];
    const float* b2     = (const float*)d_in[13];
    float* out = (float*)d_out;

    dim3 gg(TB / 128, GG / 128);   // (1024, 4)
    gemm_mfma_kernel<0><<<gg, 512, 0, stream>>>(x, W_ih0, b_ih0, b_hh0);
    lstm_kernel<0><<<BB, 256, 0, stream>>>(W_hh0, lens);
    gemm_mfma_kernel<1><<<gg, 512, 0, stream>>>(x, W_ih1, b_ih1, b_hh1);
    lstm_kernel<1><<<BB, 256, 0, stream>>>(W_hh1, lens);
    mlp_kernel<<<BB, 512, 0, stream>>>(W1, b1, W2, b2, out);
}